// Round 13
// baseline (169.662 us; speedup 1.0000x reference)
//
#include <hip/hip_runtime.h>
#include <math.h>

#define HW      1792
#define NMEM    28672
#define NCHUNK  3584          // NMEM/8 chunks of 8
#define TOPK    30
#define KSEL    48            // exact top-K chunks kept (margin 18 over TOPK)
#define NCAND   (KSEL * 8)    // 384 candidates, 6 per lane
#define SCAP1   1024          // stage-1 survivor cap (P(overflow) < 1e-40)
#define SIMB    448           // 14 p-blocks(128px) x 32 strips
#define WPS     7             // 128-n windows per strip
#define NSELB   448           // select blocks (4 pixels each)

typedef __attribute__((ext_vector_type(8))) short bf16x8;
typedef __attribute__((ext_vector_type(8))) unsigned short u16x8;
typedef __attribute__((ext_vector_type(4))) float f32x4;
typedef __attribute__((ext_vector_type(4))) _Float16 h4;
typedef unsigned long long ull;

static __device__ __forceinline__ unsigned short f2bf(float v) {
  unsigned b = __float_as_uint(v);
  return (unsigned short)((b + 0x7FFFu + ((b >> 16) & 1u)) >> 16);
}
static __device__ __forceinline__ float bf2f(unsigned short h) {
  return __uint_as_float(((unsigned)h) << 16);
}
static __device__ __forceinline__ unsigned fkey(float v) {
  return __float_as_uint(-v) & 0x7FFFFFFFu;
}
static __device__ __forceinline__ ull umax64(ull a, ull b) { return a > b ? a : b; }
static __device__ __forceinline__ ull umin64(ull a, ull b) { return a < b ? a : b; }
static __device__ __forceinline__ void gl_lds16(const void* g, void* l) {
  __builtin_amdgcn_global_load_lds(
      (const __attribute__((address_space(1))) unsigned*)g,
      (__attribute__((address_space(3))) unsigned*)l, 16, 0, 0);
}
// wave-scope LDS handoff: drain ds ops + block compiler reordering
#define WSYNC() do { asm volatile("s_waitcnt lgkmcnt(0)" ::: "memory"); \
                     __builtin_amdgcn_wave_barrier(); } while (0)

// ---------------------------------------------------------------------------
// Prep B: Bh[s][n][8] bf16-hi (s=0..7: mk, s=8..15: mk^2); mkT[n][64] fp32;
// shr_s = mem_shr/8.
// ---------------------------------------------------------------------------
__global__ __launch_bounds__(256)
void k_prep_b(const float* __restrict__ mk, const float* __restrict__ shr_in,
              unsigned short* __restrict__ Bh,
              float* __restrict__ mkT, float* __restrict__ shr_s)
{
  const int n = blockIdx.x * 256 + threadIdx.x;
  shr_s[n] = shr_in[n] * 0.125f;
  for (int cb = 0; cb < 64; cb += 8) {
    u16x8 h1, h2;
    float vv[8];
    #pragma unroll
    for (int j = 0; j < 8; ++j) {
      float v = mk[(size_t)(cb + j) * NMEM + n];
      vv[j] = v;
      h1[j] = f2bf(v);
      h2[j] = f2bf(v * v);
    }
    const int s = cb >> 3;
    *reinterpret_cast<u16x8*>(&Bh[((size_t)s * NMEM + n) * 8])       = h1;
    *reinterpret_cast<u16x8*>(&Bh[((size_t)(s + 8) * NMEM + n) * 8]) = h2;
    *reinterpret_cast<float4*>(&mkT[(size_t)n * 64 + cb])     = make_float4(vv[0], vv[1], vv[2], vv[3]);
    *reinterpret_cast<float4*>(&mkT[(size_t)n * 64 + cb + 4]) = make_float4(vv[4], vv[5], vv[6], vv[7]);
  }
}

// ---------------------------------------------------------------------------
// Prep U: Uh/Ul[s][p][8] bf16 hi/lo. s=0..7: 2*qk*qs, s=8..15: -qs. bsq[p].
// ---------------------------------------------------------------------------
__global__ __launch_bounds__(256)
void k_prep_u(const float* __restrict__ q_key, const float* __restrict__ q_sel,
              unsigned short* __restrict__ Uh, unsigned short* __restrict__ Ul,
              float* __restrict__ bsq)
{
  const int p = blockIdx.x * 256 + threadIdx.x;
  float bs = 0.f;
  for (int cb = 0; cb < 64; cb += 8) {
    u16x8 h1, l1, h2, l2;
    #pragma unroll
    for (int j = 0; j < 8; ++j) {
      int c = cb + j;
      float k = q_key[(size_t)c * HW + p];
      float s = q_sel[(size_t)c * HW + p];
      float u = 2.f * k * s;
      float w = -s;
      bs = fmaf(s * k, k, bs);
      unsigned short h = f2bf(u); h1[j] = h; l1[j] = f2bf(u - bf2f(h));
      unsigned short g = f2bf(w); h2[j] = g; l2[j] = f2bf(w - bf2f(g));
    }
    const int s = cb >> 3;
    *reinterpret_cast<u16x8*>(&Uh[((size_t)s * HW + p) * 8])       = h1;
    *reinterpret_cast<u16x8*>(&Ul[((size_t)s * HW + p) * 8])       = l1;
    *reinterpret_cast<u16x8*>(&Uh[((size_t)(s + 8) * HW + p) * 8]) = h2;
    *reinterpret_cast<u16x8*>(&Ul[((size_t)(s + 8) * HW + p) * 8]) = l2;
  }
  bsq[p] = bs;
}

// ---------------------------------------------------------------------------
// Sim kernel: 128 pixels x 7-window strip per block (448 blocks). Unchanged.
// ---------------------------------------------------------------------------
__global__ __launch_bounds__(256, 2)
void k_sim(const unsigned short* __restrict__ Uh, const unsigned short* __restrict__ Ul,
           const unsigned short* __restrict__ Bh,
           const float* __restrict__ bsq, const float* __restrict__ shr_s,
           float* __restrict__ pmax)
{
  __shared__ char smem[65536] __attribute__((aligned(16)));
  const int tid = threadIdx.x;
  const int wid = tid >> 6, lane = tid & 63;
  const int lr = lane & 15, lg = lane >> 4;
  const int pb = blockIdx.x % 14, st = blockIdx.x / 14;
  const int pw = pb * 128 + wid * 32;
  const int w0 = st * WPS;

  bf16x8 a0h[4], a0l[4], a1h[4], a1l[4];
  #pragma unroll
  for (int t = 0; t < 4; ++t) {
    const size_t e0 = ((size_t)(t * 4 + lg) * HW + pw + lr) * 8;
    const size_t e1 = e0 + 16 * 8;
    a0h[t] = *reinterpret_cast<const bf16x8*>(&Uh[e0]);
    a0l[t] = *reinterpret_cast<const bf16x8*>(&Ul[e0]);
    a1h[t] = *reinterpret_cast<const bf16x8*>(&Uh[e1]);
    a1l[t] = *reinterpret_cast<const bf16x8*>(&Ul[e1]);
  }
  float bq[2][4];
  #pragma unroll
  for (int pt = 0; pt < 2; ++pt)
    #pragma unroll
    for (int r = 0; r < 4; ++r) bq[pt][r] = bsq[pw + pt * 16 + 4 * lg + r];

  auto stage = [&](int buf, int i) {
    const int n0 = (w0 + i) * 128;
    #pragma unroll
    for (int j = 0; j < 8; ++j) {
      const int idx = j * 256 + tid;
      const int s = idx >> 7, rr = idx & 127;
      gl_lds16((const char*)Bh + ((size_t)s * NMEM + n0 + rr) * 16,
               smem + buf * 32768 + idx * 16);
    }
  };

  stage(0, 0);
  int buf = 0;
  for (int i = 0; i < WPS; ++i) {
    __syncthreads();
    if (i + 1 < WPS) stage(buf ^ 1, i + 1);

    f32x4 acc[2][8];
    #pragma unroll
    for (int a = 0; a < 2; ++a)
      #pragma unroll
      for (int b = 0; b < 8; ++b) acc[a][b] = (f32x4){0.f, 0.f, 0.f, 0.f};

    const short* lb = (const short*)(smem + buf * 32768);
    #pragma unroll
    for (int t = 0; t < 4; ++t) {
      #pragma unroll
      for (int nt = 0; nt < 8; ++nt) {
        bf16x8 bh = *reinterpret_cast<const bf16x8*>(
            &lb[((t * 4 + lg) * 128 + nt * 16 + lr) * 8]);
        acc[0][nt] = __builtin_amdgcn_mfma_f32_16x16x32_bf16(a0h[t], bh, acc[0][nt], 0, 0, 0);
        acc[0][nt] = __builtin_amdgcn_mfma_f32_16x16x32_bf16(a0l[t], bh, acc[0][nt], 0, 0, 0);
        acc[1][nt] = __builtin_amdgcn_mfma_f32_16x16x32_bf16(a1h[t], bh, acc[1][nt], 0, 0, 0);
        acc[1][nt] = __builtin_amdgcn_mfma_f32_16x16x32_bf16(a1l[t], bh, acc[1][nt], 0, 0, 0);
      }
    }

    const int wgl = w0 + i;
    const int n0 = wgl * 128;
    float shv[8];
    #pragma unroll
    for (int nt = 0; nt < 8; ++nt) shv[nt] = shr_s[n0 + nt * 16 + lr];
    #pragma unroll
    for (int pt = 0; pt < 2; ++pt) {
      #pragma unroll
      for (int r = 0; r < 4; ++r) {
        float mx = -INFINITY;
        #pragma unroll
        for (int nt = 0; nt < 8; ++nt)
          mx = fmaxf(mx, (acc[pt][nt][r] - bq[pt][r]) * shv[nt]);
        pmax[(size_t)(pw + pt * 16 + 4 * lg + r) * NCHUNK + wgl * 16 + lr] = mx;
      }
    }
    buf ^= 1;
  }
}

// ---------------------------------------------------------------------------
// Shared memory for fused select/transpose. Per wave: buf[1024] ull —
// stage-1 survivor packs, later overlaid by {cand[384], fin at 384..639}.
// ---------------------------------------------------------------------------
struct SelS {
  ull   buf[4][SCAP1];    // 32 KB
  short sl[4][KSEL];      // 384 B
  float sqk[4][64], sqs[4][64]; // 2 KB
};
union SMemU { SelS sel; float tt[64][65]; };

// ---------------------------------------------------------------------------
// Fused select(+transpose). Select: one pixel/wave, no block barriers, no LDS
// atomics. Stage 1: bitonic 64 lane-maxima -> t0 = 48th-largest lane-max
// (provably <= 48th-largest chunk-max: lane-maxima subset of chunk-maxima)
// -> compact+exact-rank survivors -> exact top-48 chunks. Stage 2: exact fp32
// sims of 384 candidates. Stage 3: top-4/lane pool rank + verified exact
// top-30 (rare exact full-rank fallback). Transpose blocks 16:1 hide select.
// ---------------------------------------------------------------------------
__global__ __launch_bounds__(256, 4)
void k_selT(const float* __restrict__ pmax, const float* __restrict__ mkT,
            const float* __restrict__ q_key, const float* __restrict__ q_sel,
            const float* __restrict__ shr_s,
            float* __restrict__ wgt, int* __restrict__ widx,
            const float* __restrict__ mv, _Float16* __restrict__ mvT)
{
  __shared__ SMemU sm;
  const int tid = threadIdx.x;

  int sg = -1, tb = -1;
  if (gridDim.x > NSELB) {
    const int g = blockIdx.x / 17, r = blockIdx.x % 17;
    if (r == 0) sg = g; else tb = g * 16 + (r - 1);
  } else {
    sg = blockIdx.x;
  }

  if (tb >= 0) {
    // ---- transpose block: 64n x 64ch fp32 -> fp16
    const int n0 = (tb % 448) * 64, ch0 = (tb / 448) * 64;
    for (int i = tid; i < 64 * 16; i += 256) {
      int r = i >> 4, c4 = (i & 15) << 2;
      float4 v = *reinterpret_cast<const float4*>(&mv[(size_t)(ch0 + r) * NMEM + n0 + c4]);
      sm.tt[r][c4] = v.x; sm.tt[r][c4 + 1] = v.y;
      sm.tt[r][c4 + 2] = v.z; sm.tt[r][c4 + 3] = v.w;
    }
    __syncthreads();
    for (int i = tid; i < 64 * 16; i += 256) {
      int r = i >> 4, c4 = (i & 15) << 2;
      h4 hv = {(_Float16)sm.tt[c4][r], (_Float16)sm.tt[c4 + 1][r],
               (_Float16)sm.tt[c4 + 2][r], (_Float16)sm.tt[c4 + 3][r]};
      *reinterpret_cast<h4*>(&mvT[(size_t)(n0 + r) * 1024 + ch0 + c4]) = hv;
    }
    return;
  }

  const int w = tid >> 6, lane = tid & 63;
  const int pix = sg * 4 + w;
  ull*   buf  = sm.sel.buf[w];
  ull*   cand = buf;           // stage-2 candidate packs (stage-1 buf dead)
  ull*   fin  = buf + NCAND;   // final 256-entry pool
  short* sl   = sm.sel.sl[w];

  sm.sel.sqk[w][lane] = q_key[(size_t)lane * HW + pix];
  sm.sel.sqs[w][lane] = q_sel[(size_t)lane * HW + pix];

  const float* pm = pmax + (size_t)pix * NCHUNK;

  // ---- pass A: per-lane max of 56 chunk maxima
  float mx = -INFINITY;
  #pragma unroll
  for (int j = 0; j < 56; ++j) mx = fmaxf(mx, pm[lane + 64 * j]);

  // ---- bitonic sort of 64 lane-maxima (ascending by lane)
  float v = mx;
  #pragma unroll
  for (int k = 2; k <= 64; k <<= 1) {
    #pragma unroll
    for (int j = k >> 1; j > 0; j >>= 1) {
      float o = __shfl_xor(v, j);
      bool keepmin = (((lane & k) == 0) == ((lane & j) == 0));
      v = keepmin ? fminf(v, o) : fmaxf(v, o);
    }
  }
  const float t0 = __shfl(v, 64 - KSEL);   // 48th-largest lane-max (safe bound)

  // ---- pass B: compact survivors (max >= t0) as packed (val,chunk) keys
  int ns0 = 0;
  #pragma unroll
  for (int j = 0; j < 56; ++j) {
    float mv2 = pm[lane + 64 * j];
    bool keep = (mv2 >= t0);
    ull ball = __ballot(keep);
    if (keep) {
      int pos = ns0 + __popcll(ball & ((1ull << lane) - 1ull));
      if (pos < SCAP1)
        buf[pos] = ((ull)(0x7FFFFFFFu - fkey(mv2)) << 32) | (unsigned)(lane + 64 * j);
    }
    ns0 += __popcll(ball);
  }
  ns0 = (ns0 < SCAP1) ? ns0 : SCAP1;   // P(overflow) < 1e-40
  WSYNC();

  // ---- stage-1 exact rank of survivors -> top-48 chunk ids (rank order)
  {
    ull e0 = (lane < ns0) ? buf[lane] : 0ull;
    ull e1 = (lane + 64 < ns0) ? buf[lane + 64] : 0ull;
    int r0 = 0, r1 = 0;
    for (int k = 0; k < ns0; ++k) {
      ull kb = buf[k];
      r0 += (kb > e0); r1 += (kb > e1);
    }
    if (e0 && r0 < KSEL) sl[r0] = (short)(unsigned)(e0 & 0xFFFFu);
    if (e1 && r1 < KSEL) sl[r1] = (short)(unsigned)(e1 & 0xFFFFu);
    for (int base = 128; base < ns0; base += 64) {        // rare (~0.3%)
      ull ee = (base + lane < ns0) ? buf[base + lane] : 0ull;
      int rr = 0;
      for (int k = 0; k < ns0; ++k) rr += (buf[k] > ee);
      if (ee && rr < KSEL) sl[rr] = (short)(unsigned)(ee & 0xFFFFu);
    }
  }
  WSYNC();

  // ---- stage 2: exact fp32 sims of the 384 candidates (6 per lane)
  const float4* k4p = reinterpret_cast<const float4*>(sm.sel.sqk[w]);
  const float4* s4p = reinterpret_cast<const float4*>(sm.sel.sqs[w]);
  ull myp[6];
  #pragma unroll
  for (int i = 0; i < 6; ++i) {
    const int c = lane + (i << 6);
    const int cc = sl[c >> 3];
    const int n = ((cc >> 4) << 7) + (cc & 15) + ((c & 7) << 4);
    const float4* mr = reinterpret_cast<const float4*>(mkT + (size_t)n * 64);
    float s0 = 0.f, s1 = 0.f, s2 = 0.f, s3 = 0.f;
    #pragma unroll
    for (int j = 0; j < 4; ++j) {
      float4 q0 = mr[4*j], q1 = mr[4*j+1], q2 = mr[4*j+2], q3 = mr[4*j+3];
      float4 a0 = k4p[4*j], a1 = k4p[4*j+1], a2 = k4p[4*j+2], a3 = k4p[4*j+3];
      float4 b0 = s4p[4*j], b1 = s4p[4*j+1], b2 = s4p[4*j+2], b3 = s4p[4*j+3];
      float d;
      d = q0.x-a0.x; s0 = fmaf(b0.x*d, d, s0);
      d = q0.y-a0.y; s1 = fmaf(b0.y*d, d, s1);
      d = q0.z-a0.z; s2 = fmaf(b0.z*d, d, s2);
      d = q0.w-a0.w; s3 = fmaf(b0.w*d, d, s3);
      d = q1.x-a1.x; s0 = fmaf(b1.x*d, d, s0);
      d = q1.y-a1.y; s1 = fmaf(b1.y*d, d, s1);
      d = q1.z-a1.z; s2 = fmaf(b1.z*d, d, s2);
      d = q1.w-a1.w; s3 = fmaf(b1.w*d, d, s3);
      d = q2.x-a2.x; s0 = fmaf(b2.x*d, d, s0);
      d = q2.y-a2.y; s1 = fmaf(b2.y*d, d, s1);
      d = q2.z-a2.z; s2 = fmaf(b2.z*d, d, s2);
      d = q2.w-a2.w; s3 = fmaf(b2.w*d, d, s3);
      d = q3.x-a3.x; s0 = fmaf(b3.x*d, d, s0);
      d = q3.y-a3.y; s1 = fmaf(b3.y*d, d, s1);
      d = q3.z-a3.z; s2 = fmaf(b3.z*d, d, s2);
      d = q3.w-a3.w; s3 = fmaf(b3.w*d, d, s3);
    }
    float sv = -((s0 + s1) + (s2 + s3)) * shr_s[n];
    ull pk = ((ull)(0x7FFFFFFFu - fkey(sv)) << 32) |
             (ull)(0xFFFFFFFFu - (unsigned)n);
    cand[c] = pk;
    myp[i] = pk;
  }
  WSYNC();

  // ---- stage 3: top-4/lane -> 256 pool -> exact rank -> verified top-30
  ull p0 = 0, p1 = 0, p2 = 0, p3 = 0;
  #pragma unroll
  for (int i = 0; i < 6; ++i) {
    ull k = myp[i], m;
    m = umax64(p0, k); k = umin64(p0, k); p0 = m;
    m = umax64(p1, k); k = umin64(p1, k); p1 = m;
    m = umax64(p2, k); k = umin64(p2, k); p2 = m;
    m = umax64(p3, k); k = umin64(p3, k); p3 = m;
  }
  fin[lane * 4 + 0] = p0; fin[lane * 4 + 1] = p1;
  fin[lane * 4 + 2] = p2; fin[lane * 4 + 3] = p3;
  WSYNC();

  int r0 = 0, r1 = 0, r2 = 0, r3 = 0;
  for (int k = 0; k < 256; ++k) {
    ull kb = fin[k];
    r0 += (kb > p0); r1 += (kb > p1); r2 += (kb > p2); r3 += (kb > p3);
  }
  ull c30 = (r0 == TOPK - 1) ? p0 : (r1 == TOPK - 1) ? p1 :
            (r2 == TOPK - 1) ? p2 : (r3 == TOPK - 1) ? p3 : 0ull;
  ull ball = __ballot(c30 != 0ull);
  ull k30 = __shfl(c30, (int)(__ffsll((long long)ball) - 1));

  int cnt = 0;
  #pragma unroll
  for (int i = 0; i < 6; ++i) cnt += (myp[i] > k30);
  #pragma unroll
  for (int off = 32; off > 0; off >>= 1) cnt += __shfl_xor(cnt, off);
  const bool ok = (cnt == TOPK - 1);      // wave-uniform

  if (ok) {
    float v0 = -__uint_as_float(0x7FFFFFFFu - (unsigned)(p0 >> 32));
    float v1 = -__uint_as_float(0x7FFFFFFFu - (unsigned)(p1 >> 32));
    float v2 = -__uint_as_float(0x7FFFFFFFu - (unsigned)(p2 >> 32));
    float v3 = -__uint_as_float(0x7FFFFFFFu - (unsigned)(p3 >> 32));
    float e0 = (r0 < TOPK) ? expf(v0) : 0.f;
    float e1 = (r1 < TOPK) ? expf(v1) : 0.f;
    float e2 = (r2 < TOPK) ? expf(v2) : 0.f;
    float e3 = (r3 < TOPK) ? expf(v3) : 0.f;
    float es = e0 + e1 + e2 + e3;
    #pragma unroll
    for (int off = 32; off > 0; off >>= 1) es += __shfl_xor(es, off);
    if (r0 < TOPK) { wgt[(size_t)pix*32 + r0] = e0/es; widx[(size_t)pix*32 + r0] = (int)(0xFFFFFFFFu - (unsigned)(p0 & 0xFFFFFFFFu)); }
    if (r1 < TOPK) { wgt[(size_t)pix*32 + r1] = e1/es; widx[(size_t)pix*32 + r1] = (int)(0xFFFFFFFFu - (unsigned)(p1 & 0xFFFFFFFFu)); }
    if (r2 < TOPK) { wgt[(size_t)pix*32 + r2] = e2/es; widx[(size_t)pix*32 + r2] = (int)(0xFFFFFFFFu - (unsigned)(p2 & 0xFFFFFFFFu)); }
    if (r3 < TOPK) { wgt[(size_t)pix*32 + r3] = e3/es; widx[(size_t)pix*32 + r3] = (int)(0xFFFFFFFFu - (unsigned)(p3 & 0xFFFFFFFFu)); }
  } else {
    // exact full-rank fallback (rare, ~1% of pixels)
    int rr[6];
    #pragma unroll
    for (int i = 0; i < 6; ++i) rr[i] = 0;
    for (int k = 0; k < NCAND; ++k) {
      ull kb = cand[k];
      #pragma unroll
      for (int i = 0; i < 6; ++i) rr[i] += (kb > myp[i]);
    }
    float ev[6]; float es = 0.f;
    #pragma unroll
    for (int i = 0; i < 6; ++i) {
      float vv = -__uint_as_float(0x7FFFFFFFu - (unsigned)(myp[i] >> 32));
      ev[i] = (rr[i] < TOPK) ? expf(vv) : 0.f;
      es += ev[i];
    }
    #pragma unroll
    for (int off = 32; off > 0; off >>= 1) es += __shfl_xor(es, off);
    #pragma unroll
    for (int i = 0; i < 6; ++i) {
      if (rr[i] < TOPK) {
        wgt [(size_t)pix * 32 + rr[i]] = ev[i] / es;
        widx[(size_t)pix * 32 + rr[i]] = (int)(0xFFFFFFFFu - (unsigned)(myp[i] & 0xFFFFFFFFu));
      }
    }
  }
}

// ---------------------------------------------------------------------------
// Standalone fp16 transpose (fallback, overlay mode)
// ---------------------------------------------------------------------------
__global__ __launch_bounds__(256)
void k_transpose_h(const float* __restrict__ mv, _Float16* __restrict__ mvT)
{
  __shared__ float t[64][65];
  const int n0 = blockIdx.x * 64, ch0 = blockIdx.y * 64;
  const int tid = threadIdx.x;
  for (int i = tid; i < 64 * 16; i += 256) {
    int r = i >> 4, c4 = (i & 15) << 2;
    float4 v = *reinterpret_cast<const float4*>(&mv[(size_t)(ch0 + r) * NMEM + n0 + c4]);
    t[r][c4] = v.x; t[r][c4 + 1] = v.y; t[r][c4 + 2] = v.z; t[r][c4 + 3] = v.w;
  }
  __syncthreads();
  for (int i = tid; i < 64 * 16; i += 256) {
    int r = i >> 4, c4 = (i & 15) << 2;
    h4 hv = {(_Float16)t[c4][r], (_Float16)t[c4 + 1][r],
             (_Float16)t[c4 + 2][r], (_Float16)t[c4 + 3][r]};
    *reinterpret_cast<h4*>(&mvT[(size_t)(n0 + r) * 1024 + ch0 + c4]) = hv;
  }
}

// ---------------------------------------------------------------------------
// Gather (fp16 source): out[ch][p] = sum_k w[p][k] * mvT[idx[p][k]][ch]
// ---------------------------------------------------------------------------
__global__ __launch_bounds__(256)
void k_gather_h(const _Float16* __restrict__ mvT, const float* __restrict__ wgt,
                const int* __restrict__ widx, float* __restrict__ out)
{
  __shared__ float sw[8][TOPK];
  __shared__ int   si[8][TOPK];
  __shared__ float sbuf[256][9];
  const int p0 = blockIdx.x * 8, chg = blockIdx.y * 256;
  const int tid = threadIdx.x;

  for (int i = tid; i < 8 * TOPK; i += 256) {
    int q = i / TOPK, k = i - q * TOPK;
    sw[q][k] = wgt [(size_t)(p0 + q) * 32 + k];
    si[q][k] = widx[(size_t)(p0 + q) * 32 + k];
  }
  __syncthreads();

  const int ch = chg + tid;
  #pragma unroll 2
  for (int q = 0; q < 8; ++q) {
    float a = 0.f;
    #pragma unroll
    for (int k = 0; k < TOPK; ++k)
      a = fmaf(sw[q][k], (float)mvT[(size_t)si[q][k] * 1024 + ch], a);
    sbuf[tid][q] = a;
  }
  __syncthreads();

  for (int i = tid; i < 256 * 8; i += 256) {
    int cl = i >> 3, q = i & 7;
    out[(size_t)(chg + cl) * HW + p0 + q] = sbuf[cl][q];
  }
}

// ---------------------------------------------------------------------------
// Gather (fp32 strided source, raw fallback)
// ---------------------------------------------------------------------------
__global__ __launch_bounds__(256)
void k_gather_f(const float* __restrict__ src, const float* __restrict__ wgt,
                const int* __restrict__ widx, float* __restrict__ out,
                long n_stride, long ch_stride)
{
  __shared__ float sw[8][TOPK];
  __shared__ int   si[8][TOPK];
  __shared__ float sbuf[256][9];
  const int p0 = blockIdx.x * 8, chg = blockIdx.y * 256;
  const int tid = threadIdx.x;

  for (int i = tid; i < 8 * TOPK; i += 256) {
    int q = i / TOPK, k = i - q * TOPK;
    sw[q][k] = wgt [(size_t)(p0 + q) * 32 + k];
    si[q][k] = widx[(size_t)(p0 + q) * 32 + k];
  }
  __syncthreads();

  const int ch = chg + tid;
  #pragma unroll 2
  for (int q = 0; q < 8; ++q) {
    float a = 0.f;
    #pragma unroll
    for (int k = 0; k < TOPK; ++k)
      a = fmaf(sw[q][k], src[(size_t)si[q][k] * n_stride + (size_t)ch * ch_stride], a);
    sbuf[tid][q] = a;
  }
  __syncthreads();

  for (int i = tid; i < 256 * 8; i += 256) {
    int cl = i >> 3, q = i & 7;
    out[(size_t)(chg + cl) * HW + p0 + q] = sbuf[cl][q];
  }
}

// ---------------------------------------------------------------------------
extern "C" void kernel_launch(void* const* d_in, const int* in_sizes, int n_in,
                              void* d_out, int out_size, void* d_ws, size_t ws_size,
                              hipStream_t stream)
{
  (void)in_sizes; (void)n_in; (void)out_size;
  const float* q_key     = (const float*)d_in[0];
  const float* q_sel     = (const float*)d_in[1];
  const float* mem_key   = (const float*)d_in[2];
  const float* mem_shr   = (const float*)d_in[3];
  const float* mem_value = (const float*)d_in[4];
  float* out = (float*)d_out;

  char* ws = (char*)d_ws;
  size_t off = 0;
  auto alloc = [&](size_t b) { size_t c = off; off = (off + b + 255) & ~(size_t)255; return c; };
  size_t o_w   = alloc((size_t)HW * 32 * 4);
  size_t o_wi  = alloc((size_t)HW * 32 * 4);
  size_t o_pr  = off;                              // overlay point (fallback)
  size_t o_bh  = alloc((size_t)NMEM * 128 * 2);    // 7.34 MB
  size_t o_uh  = alloc((size_t)HW * 128 * 2);
  size_t o_ul  = alloc((size_t)HW * 128 * 2);
  size_t o_bsq = alloc((size_t)HW * 4);
  size_t o_shr = alloc((size_t)NMEM * 4);
  size_t o_mkT = alloc((size_t)NMEM * 64 * 4);     // 7.34 MB
  size_t o_pm  = alloc((size_t)HW * NCHUNK * 4);   // 25.7 MB
  size_t o_end = off;

  float*          wg   = (float*)(ws + o_w);
  int*            wi   = (int*)  (ws + o_wi);
  unsigned short* Bh   = (unsigned short*)(ws + o_bh);
  unsigned short* Uh   = (unsigned short*)(ws + o_uh);
  unsigned short* Ul   = (unsigned short*)(ws + o_ul);
  float*          bsq  = (float*)(ws + o_bsq);
  float*          shr  = (float*)(ws + o_shr);
  float*          mkT  = (float*)(ws + o_mkT);
  float*          pmx  = (float*)(ws + o_pm);

  const size_t mvh_sz = (size_t)NMEM * 1024 * 2;   // 58.7 MB fp16

  k_prep_b<<<NMEM / 256, 256, 0, stream>>>(mem_key, mem_shr, Bh, mkT, shr);
  k_prep_u<<<HW / 256, 256, 0, stream>>>(q_key, q_sel, Uh, Ul, bsq);
  k_sim<<<SIMB, 256, 0, stream>>>(Uh, Ul, Bh, bsq, shr, pmx);

  if (ws_size >= o_end + mvh_sz) {
    // fused: select (448 blocks, 4px each) + transpose (7168), 1:16
    _Float16* mvT = (_Float16*)(ws + o_end);
    k_selT<<<NSELB * 17, 256, 0, stream>>>(pmx, mkT, q_key, q_sel, shr,
                                           wg, wi, mem_value, mvT);
    k_gather_h<<<dim3(HW / 8, 4), 256, 0, stream>>>(mvT, wg, wi, out);
  } else if (ws_size >= o_pr + mvh_sz) {
    // fallback: select only, then transpose into overlay region
    k_selT<<<NSELB, 256, 0, stream>>>(pmx, mkT, q_key, q_sel, shr,
                                      wg, wi, mem_value, nullptr);
    _Float16* mvT = (_Float16*)(ws + o_pr);        // Bh..pmx dead after select
    k_transpose_h<<<dim3(NMEM / 64, 16), 256, 0, stream>>>(mem_value, mvT);
    k_gather_h<<<dim3(HW / 8, 4), 256, 0, stream>>>(mvT, wg, wi, out);
  } else {
    k_selT<<<NSELB, 256, 0, stream>>>(pmx, mkT, q_key, q_sel, shr,
                                      wg, wi, mem_value, nullptr);
    k_gather_f<<<dim3(HW / 8, 4), 256, 0, stream>>>(
        mem_value, wg, wi, out, 1, NMEM);
  }
}

// Round 14
// 150.211 us; speedup vs baseline: 1.1295x; 1.1295x over previous
//
#include <hip/hip_runtime.h>
#include <math.h>

#define HW      1792
#define NMEM    28672
#define NCHUNK  3584          // NMEM/8 chunks of 8
#define TOPK    30
#define KSEL    48            // threshold rank over chunk maxima
#define SCAP    64            // survivor chunk cap (ties beyond 48: ~never)
#define SIMB    448           // 14 p-blocks(128px) x 32 strips
#define WPS     7             // 128-n windows per strip

typedef __attribute__((ext_vector_type(8))) short bf16x8;
typedef __attribute__((ext_vector_type(8))) unsigned short u16x8;
typedef __attribute__((ext_vector_type(4))) float f32x4;
typedef __attribute__((ext_vector_type(4))) _Float16 h4;
typedef unsigned long long ull;

static __device__ __forceinline__ unsigned short f2bf(float v) {
  unsigned b = __float_as_uint(v);
  return (unsigned short)((b + 0x7FFFu + ((b >> 16) & 1u)) >> 16);
}
static __device__ __forceinline__ float bf2f(unsigned short h) {
  return __uint_as_float(((unsigned)h) << 16);
}
static __device__ __forceinline__ unsigned fkey(float v) {
  return __float_as_uint(-v) & 0x7FFFFFFFu;   // smaller key = larger value
}
static __device__ __forceinline__ ull umax64(ull a, ull b) { return a > b ? a : b; }
static __device__ __forceinline__ ull umin64(ull a, ull b) { return a < b ? a : b; }
static __device__ __forceinline__ void gl_lds16(const void* g, void* l) {
  __builtin_amdgcn_global_load_lds(
      (const __attribute__((address_space(1))) unsigned*)g,
      (__attribute__((address_space(3))) unsigned*)l, 16, 0, 0);
}
#define WSYNC() do { asm volatile("s_waitcnt lgkmcnt(0)" ::: "memory"); \
                     __builtin_amdgcn_wave_barrier(); } while (0)

// ---------------------------------------------------------------------------
// Prep B: Bh[s][n][8] bf16-hi (s=0..7: mk, s=8..15: mk^2); mkT[n][64] fp32;
// shr_s = mem_shr/8.
// ---------------------------------------------------------------------------
__global__ __launch_bounds__(256)
void k_prep_b(const float* __restrict__ mk, const float* __restrict__ shr_in,
              unsigned short* __restrict__ Bh,
              float* __restrict__ mkT, float* __restrict__ shr_s)
{
  const int n = blockIdx.x * 256 + threadIdx.x;
  shr_s[n] = shr_in[n] * 0.125f;
  for (int cb = 0; cb < 64; cb += 8) {
    u16x8 h1, h2;
    float vv[8];
    #pragma unroll
    for (int j = 0; j < 8; ++j) {
      float v = mk[(size_t)(cb + j) * NMEM + n];
      vv[j] = v;
      h1[j] = f2bf(v);
      h2[j] = f2bf(v * v);
    }
    const int s = cb >> 3;
    *reinterpret_cast<u16x8*>(&Bh[((size_t)s * NMEM + n) * 8])       = h1;
    *reinterpret_cast<u16x8*>(&Bh[((size_t)(s + 8) * NMEM + n) * 8]) = h2;
    *reinterpret_cast<float4*>(&mkT[(size_t)n * 64 + cb])     = make_float4(vv[0], vv[1], vv[2], vv[3]);
    *reinterpret_cast<float4*>(&mkT[(size_t)n * 64 + cb + 4]) = make_float4(vv[4], vv[5], vv[6], vv[7]);
  }
}

// ---------------------------------------------------------------------------
// Prep U: Uh/Ul[s][p][8] bf16 hi/lo. s=0..7: 2*qk*qs, s=8..15: -qs. bsq[p].
// ---------------------------------------------------------------------------
__global__ __launch_bounds__(256)
void k_prep_u(const float* __restrict__ q_key, const float* __restrict__ q_sel,
              unsigned short* __restrict__ Uh, unsigned short* __restrict__ Ul,
              float* __restrict__ bsq)
{
  const int p = blockIdx.x * 256 + threadIdx.x;
  float bs = 0.f;
  for (int cb = 0; cb < 64; cb += 8) {
    u16x8 h1, l1, h2, l2;
    #pragma unroll
    for (int j = 0; j < 8; ++j) {
      int c = cb + j;
      float k = q_key[(size_t)c * HW + p];
      float s = q_sel[(size_t)c * HW + p];
      float u = 2.f * k * s;
      float w = -s;
      bs = fmaf(s * k, k, bs);
      unsigned short h = f2bf(u); h1[j] = h; l1[j] = f2bf(u - bf2f(h));
      unsigned short g = f2bf(w); h2[j] = g; l2[j] = f2bf(w - bf2f(g));
    }
    const int s = cb >> 3;
    *reinterpret_cast<u16x8*>(&Uh[((size_t)s * HW + p) * 8])       = h1;
    *reinterpret_cast<u16x8*>(&Ul[((size_t)s * HW + p) * 8])       = l1;
    *reinterpret_cast<u16x8*>(&Uh[((size_t)(s + 8) * HW + p) * 8]) = h2;
    *reinterpret_cast<u16x8*>(&Ul[((size_t)(s + 8) * HW + p) * 8]) = l2;
  }
  bsq[p] = bs;
}

// ---------------------------------------------------------------------------
// Sim kernel: 128 pixels x 7-window strip per block (448 blocks). Unchanged.
// ---------------------------------------------------------------------------
__global__ __launch_bounds__(256, 2)
void k_sim(const unsigned short* __restrict__ Uh, const unsigned short* __restrict__ Ul,
           const unsigned short* __restrict__ Bh,
           const float* __restrict__ bsq, const float* __restrict__ shr_s,
           float* __restrict__ pmax)
{
  __shared__ char smem[65536] __attribute__((aligned(16)));
  const int tid = threadIdx.x;
  const int wid = tid >> 6, lane = tid & 63;
  const int lr = lane & 15, lg = lane >> 4;
  const int pb = blockIdx.x % 14, st = blockIdx.x / 14;
  const int pw = pb * 128 + wid * 32;
  const int w0 = st * WPS;

  bf16x8 a0h[4], a0l[4], a1h[4], a1l[4];
  #pragma unroll
  for (int t = 0; t < 4; ++t) {
    const size_t e0 = ((size_t)(t * 4 + lg) * HW + pw + lr) * 8;
    const size_t e1 = e0 + 16 * 8;
    a0h[t] = *reinterpret_cast<const bf16x8*>(&Uh[e0]);
    a0l[t] = *reinterpret_cast<const bf16x8*>(&Ul[e0]);
    a1h[t] = *reinterpret_cast<const bf16x8*>(&Uh[e1]);
    a1l[t] = *reinterpret_cast<const bf16x8*>(&Ul[e1]);
  }
  float bq[2][4];
  #pragma unroll
  for (int pt = 0; pt < 2; ++pt)
    #pragma unroll
    for (int r = 0; r < 4; ++r) bq[pt][r] = bsq[pw + pt * 16 + 4 * lg + r];

  auto stage = [&](int buf, int i) {
    const int n0 = (w0 + i) * 128;
    #pragma unroll
    for (int j = 0; j < 8; ++j) {
      const int idx = j * 256 + tid;
      const int s = idx >> 7, rr = idx & 127;
      gl_lds16((const char*)Bh + ((size_t)s * NMEM + n0 + rr) * 16,
               smem + buf * 32768 + idx * 16);
    }
  };

  stage(0, 0);
  int buf = 0;
  for (int i = 0; i < WPS; ++i) {
    __syncthreads();
    if (i + 1 < WPS) stage(buf ^ 1, i + 1);

    f32x4 acc[2][8];
    #pragma unroll
    for (int a = 0; a < 2; ++a)
      #pragma unroll
      for (int b = 0; b < 8; ++b) acc[a][b] = (f32x4){0.f, 0.f, 0.f, 0.f};

    const short* lb = (const short*)(smem + buf * 32768);
    #pragma unroll
    for (int t = 0; t < 4; ++t) {
      #pragma unroll
      for (int nt = 0; nt < 8; ++nt) {
        bf16x8 bh = *reinterpret_cast<const bf16x8*>(
            &lb[((t * 4 + lg) * 128 + nt * 16 + lr) * 8]);
        acc[0][nt] = __builtin_amdgcn_mfma_f32_16x16x32_bf16(a0h[t], bh, acc[0][nt], 0, 0, 0);
        acc[0][nt] = __builtin_amdgcn_mfma_f32_16x16x32_bf16(a0l[t], bh, acc[0][nt], 0, 0, 0);
        acc[1][nt] = __builtin_amdgcn_mfma_f32_16x16x32_bf16(a1h[t], bh, acc[1][nt], 0, 0, 0);
        acc[1][nt] = __builtin_amdgcn_mfma_f32_16x16x32_bf16(a1l[t], bh, acc[1][nt], 0, 0, 0);
      }
    }

    const int wgl = w0 + i;
    const int n0 = wgl * 128;
    float shv[8];
    #pragma unroll
    for (int nt = 0; nt < 8; ++nt) shv[nt] = shr_s[n0 + nt * 16 + lr];
    #pragma unroll
    for (int pt = 0; pt < 2; ++pt) {
      #pragma unroll
      for (int r = 0; r < 4; ++r) {
        float mx = -INFINITY;
        #pragma unroll
        for (int nt = 0; nt < 8; ++nt)
          mx = fmaxf(mx, (acc[pt][nt][r] - bq[pt][r]) * shv[nt]);
        pmax[(size_t)(pw + pt * 16 + 4 * lg + r) * NCHUNK + wgl * 16 + lr] = mx;
      }
    }
    buf ^= 1;
  }
}

// ---------------------------------------------------------------------------
// Select: one pixel per wave, 4 waves/block, 448 blocks. No block barriers,
// no LDS atomics, no quadratic step.
// Stage 1: register bisection -> exact 48th-largest chunk-max key T48.
//          (chunk-max < T48 => chunk holds no approx-top-30 element; exact.)
// Stage 2: exact fp32 sims of <=512 candidates from surviving chunks.
// Stage 3: top-4/lane -> 256 pool -> broadcast rank -> verified top-30
//          (exact full-rank fallback on verify miss, ~1e-4 of pixels).
// ---------------------------------------------------------------------------
__global__ __launch_bounds__(256, 2)
void k_select(const float* __restrict__ pmax, const float* __restrict__ mkT,
              const float* __restrict__ q_key, const float* __restrict__ q_sel,
              const float* __restrict__ shr_s,
              float* __restrict__ wgt, int* __restrict__ widx)
{
  __shared__ ull   cand[4][512];        // 16 KB candidate packs
  __shared__ ull   fin[4][256];         // 8 KB final pool
  __shared__ short sl[4][SCAP];         // survivor chunk ids
  __shared__ float sqk[4][64], sqs[4][64];

  const int w = threadIdx.x >> 6, lane = threadIdx.x & 63;
  const int pix = blockIdx.x * 4 + w;
  ull*   cd = cand[w];
  ull*   fn = fin[w];
  short* sv = sl[w];

  sqk[w][lane] = q_key[(size_t)lane * HW + pix];
  sqs[w][lane] = q_sel[(size_t)lane * HW + pix];

  // ---- load 56 chunk-max keys into registers (single pmax pass)
  unsigned kk[56];
  const float* pm = pmax + (size_t)pix * NCHUNK;
  #pragma unroll
  for (int j = 0; j < 56; ++j) kk[j] = fkey(pm[lane + 64 * j]);

  // ---- stage 1: bisection for smallest T with count(kk <= T) >= KSEL
  unsigned lo = 0, hi = 0x7FFFFFFFu;
  while (lo < hi) {                      // wave-uniform, <= 31 iterations
    unsigned mid = (lo + hi) >> 1;
    int c = 0;
    #pragma unroll
    for (int j = 0; j < 56; ++j) c += (kk[j] <= mid);
    #pragma unroll
    for (int off = 1; off < 64; off <<= 1) c += __shfl_xor(c, off);
    if (c >= KSEL) hi = mid; else lo = mid + 1;
  }
  const unsigned T48 = lo;

  // ---- compact surviving chunks (ballot, deterministic order, no rank)
  int ns = 0;
  #pragma unroll
  for (int j = 0; j < 56; ++j) {
    bool keep = (kk[j] <= T48);
    ull ball = __ballot(keep);
    if (keep) {
      int pos = ns + __popcll(ball & ((1ull << lane) - 1ull));
      if (pos < SCAP) sv[pos] = (short)(lane + 64 * j);
    }
    ns += __popcll(ball);
  }
  ns = (ns < SCAP) ? ns : SCAP;
  const int NC = ns * 8;                 // 384..512 typically
  WSYNC();

  // ---- stage 2: exact fp32 sims (<= 8 candidates per lane, predicated)
  const float4* k4p = reinterpret_cast<const float4*>(sqk[w]);
  const float4* s4p = reinterpret_cast<const float4*>(sqs[w]);
  ull myp[8];
  #pragma unroll
  for (int i = 0; i < 8; ++i) {
    myp[i] = 0ull;
    const int c = lane + (i << 6);
    if (c < NC) {
      const int cc = sv[c >> 3];
      const int n = ((cc >> 4) << 7) + (cc & 15) + ((c & 7) << 4);
      const float4* mr = reinterpret_cast<const float4*>(mkT + (size_t)n * 64);
      float s0 = 0.f, s1 = 0.f, s2 = 0.f, s3 = 0.f;
      #pragma unroll
      for (int j = 0; j < 4; ++j) {
        float4 q0 = mr[4*j], q1 = mr[4*j+1], q2 = mr[4*j+2], q3 = mr[4*j+3];
        float4 a0 = k4p[4*j], a1 = k4p[4*j+1], a2 = k4p[4*j+2], a3 = k4p[4*j+3];
        float4 b0 = s4p[4*j], b1 = s4p[4*j+1], b2 = s4p[4*j+2], b3 = s4p[4*j+3];
        float d;
        d = q0.x-a0.x; s0 = fmaf(b0.x*d, d, s0);
        d = q0.y-a0.y; s1 = fmaf(b0.y*d, d, s1);
        d = q0.z-a0.z; s2 = fmaf(b0.z*d, d, s2);
        d = q0.w-a0.w; s3 = fmaf(b0.w*d, d, s3);
        d = q1.x-a1.x; s0 = fmaf(b1.x*d, d, s0);
        d = q1.y-a1.y; s1 = fmaf(b1.y*d, d, s1);
        d = q1.z-a1.z; s2 = fmaf(b1.z*d, d, s2);
        d = q1.w-a1.w; s3 = fmaf(b1.w*d, d, s3);
        d = q2.x-a2.x; s0 = fmaf(b2.x*d, d, s0);
        d = q2.y-a2.y; s1 = fmaf(b2.y*d, d, s1);
        d = q2.z-a2.z; s2 = fmaf(b2.z*d, d, s2);
        d = q2.w-a2.w; s3 = fmaf(b2.w*d, d, s3);
        d = q3.x-a3.x; s0 = fmaf(b3.x*d, d, s0);
        d = q3.y-a3.y; s1 = fmaf(b3.y*d, d, s1);
        d = q3.z-a3.z; s2 = fmaf(b3.z*d, d, s2);
        d = q3.w-a3.w; s3 = fmaf(b3.w*d, d, s3);
      }
      float svv = -((s0 + s1) + (s2 + s3)) * shr_s[n];
      myp[i] = ((ull)(0x7FFFFFFFu - fkey(svv)) << 32) |
               (ull)(0xFFFFFFFFu - (unsigned)n);
    }
    cd[lane + (i << 6)] = myp[i];
  }
  WSYNC();

  // ---- stage 3: top-4/lane -> 256 pool -> broadcast rank -> verify
  ull p0 = 0, p1 = 0, p2 = 0, p3 = 0;
  #pragma unroll
  for (int i = 0; i < 8; ++i) {
    ull k = myp[i], m;
    m = umax64(p0, k); k = umin64(p0, k); p0 = m;
    m = umax64(p1, k); k = umin64(p1, k); p1 = m;
    m = umax64(p2, k); k = umin64(p2, k); p2 = m;
    m = umax64(p3, k); k = umin64(p3, k); p3 = m;
  }
  fn[lane * 4 + 0] = p0; fn[lane * 4 + 1] = p1;
  fn[lane * 4 + 2] = p2; fn[lane * 4 + 3] = p3;
  WSYNC();

  int r0 = 0, r1 = 0, r2 = 0, r3 = 0;
  for (int k = 0; k < 256; ++k) {
    ull kb = fn[k];
    r0 += (kb > p0); r1 += (kb > p1); r2 += (kb > p2); r3 += (kb > p3);
  }
  ull c30 = (r0 == TOPK - 1) ? p0 : (r1 == TOPK - 1) ? p1 :
            (r2 == TOPK - 1) ? p2 : (r3 == TOPK - 1) ? p3 : 0ull;
  ull ball2 = __ballot(c30 != 0ull);
  ull k30 = __shfl(c30, (int)(__ffsll((long long)ball2) - 1));

  int cnt = 0;
  #pragma unroll
  for (int i = 0; i < 8; ++i) cnt += (myp[i] > k30);
  #pragma unroll
  for (int off = 32; off > 0; off >>= 1) cnt += __shfl_xor(cnt, off);
  const bool ok = (cnt == TOPK - 1);     // wave-uniform

  if (ok) {
    float v0 = -__uint_as_float(0x7FFFFFFFu - (unsigned)(p0 >> 32));
    float v1 = -__uint_as_float(0x7FFFFFFFu - (unsigned)(p1 >> 32));
    float v2 = -__uint_as_float(0x7FFFFFFFu - (unsigned)(p2 >> 32));
    float v3 = -__uint_as_float(0x7FFFFFFFu - (unsigned)(p3 >> 32));
    float e0 = (r0 < TOPK) ? expf(v0) : 0.f;
    float e1 = (r1 < TOPK) ? expf(v1) : 0.f;
    float e2 = (r2 < TOPK) ? expf(v2) : 0.f;
    float e3 = (r3 < TOPK) ? expf(v3) : 0.f;
    float es = e0 + e1 + e2 + e3;
    #pragma unroll
    for (int off = 32; off > 0; off >>= 1) es += __shfl_xor(es, off);
    if (r0 < TOPK) { wgt[(size_t)pix*32 + r0] = e0/es; widx[(size_t)pix*32 + r0] = (int)(0xFFFFFFFFu - (unsigned)(p0 & 0xFFFFFFFFu)); }
    if (r1 < TOPK) { wgt[(size_t)pix*32 + r1] = e1/es; widx[(size_t)pix*32 + r1] = (int)(0xFFFFFFFFu - (unsigned)(p1 & 0xFFFFFFFFu)); }
    if (r2 < TOPK) { wgt[(size_t)pix*32 + r2] = e2/es; widx[(size_t)pix*32 + r2] = (int)(0xFFFFFFFFu - (unsigned)(p2 & 0xFFFFFFFFu)); }
    if (r3 < TOPK) { wgt[(size_t)pix*32 + r3] = e3/es; widx[(size_t)pix*32 + r3] = (int)(0xFFFFFFFFu - (unsigned)(p3 & 0xFFFFFFFFu)); }
  } else {
    // exact full-rank fallback over all candidates (rare)
    int rr[8];
    #pragma unroll
    for (int i = 0; i < 8; ++i) rr[i] = 0;
    for (int k = 0; k < NC; ++k) {
      ull kb = cd[k];
      #pragma unroll
      for (int i = 0; i < 8; ++i) rr[i] += (kb > myp[i]);
    }
    float ev[8]; float es = 0.f;
    #pragma unroll
    for (int i = 0; i < 8; ++i) {
      float vv = -__uint_as_float(0x7FFFFFFFu - (unsigned)(myp[i] >> 32));
      ev[i] = (myp[i] != 0ull && rr[i] < TOPK) ? expf(vv) : 0.f;
      es += ev[i];
    }
    #pragma unroll
    for (int off = 32; off > 0; off >>= 1) es += __shfl_xor(es, off);
    #pragma unroll
    for (int i = 0; i < 8; ++i) {
      if (myp[i] != 0ull && rr[i] < TOPK) {
        wgt [(size_t)pix * 32 + rr[i]] = ev[i] / es;
        widx[(size_t)pix * 32 + rr[i]] = (int)(0xFFFFFFFFu - (unsigned)(myp[i] & 0xFFFFFFFFu));
      }
    }
  }
}

// ---------------------------------------------------------------------------
// Transpose: mem_value fp32 [1024][N] -> mvT fp16 [N][1024]. 8 blocks/CU.
// ---------------------------------------------------------------------------
__global__ __launch_bounds__(256)
void k_transpose_h(const float* __restrict__ mv, _Float16* __restrict__ mvT)
{
  __shared__ float t[64][65];
  const int n0 = blockIdx.x * 64, ch0 = blockIdx.y * 64;
  const int tid = threadIdx.x;
  for (int i = tid; i < 64 * 16; i += 256) {
    int r = i >> 4, c4 = (i & 15) << 2;
    float4 v = *reinterpret_cast<const float4*>(&mv[(size_t)(ch0 + r) * NMEM + n0 + c4]);
    t[r][c4] = v.x; t[r][c4 + 1] = v.y; t[r][c4 + 2] = v.z; t[r][c4 + 3] = v.w;
  }
  __syncthreads();
  for (int i = tid; i < 64 * 16; i += 256) {
    int r = i >> 4, c4 = (i & 15) << 2;
    h4 hv = {(_Float16)t[c4][r], (_Float16)t[c4 + 1][r],
             (_Float16)t[c4 + 2][r], (_Float16)t[c4 + 3][r]};
    *reinterpret_cast<h4*>(&mvT[(size_t)(n0 + r) * 1024 + ch0 + c4]) = hv;
  }
}

// ---------------------------------------------------------------------------
// Gather (fp16 source): out[ch][p] = sum_k w[p][k] * mvT[idx[p][k]][ch]
// ---------------------------------------------------------------------------
__global__ __launch_bounds__(256)
void k_gather_h(const _Float16* __restrict__ mvT, const float* __restrict__ wgt,
                const int* __restrict__ widx, float* __restrict__ out)
{
  __shared__ float sw[8][TOPK];
  __shared__ int   si[8][TOPK];
  __shared__ float sbuf[256][9];
  const int p0 = blockIdx.x * 8, chg = blockIdx.y * 256;
  const int tid = threadIdx.x;

  for (int i = tid; i < 8 * TOPK; i += 256) {
    int q = i / TOPK, k = i - q * TOPK;
    sw[q][k] = wgt [(size_t)(p0 + q) * 32 + k];
    si[q][k] = widx[(size_t)(p0 + q) * 32 + k];
  }
  __syncthreads();

  const int ch = chg + tid;
  #pragma unroll 2
  for (int q = 0; q < 8; ++q) {
    float a = 0.f;
    #pragma unroll
    for (int k = 0; k < TOPK; ++k)
      a = fmaf(sw[q][k], (float)mvT[(size_t)si[q][k] * 1024 + ch], a);
    sbuf[tid][q] = a;
  }
  __syncthreads();

  for (int i = tid; i < 256 * 8; i += 256) {
    int cl = i >> 3, q = i & 7;
    out[(size_t)(chg + cl) * HW + p0 + q] = sbuf[cl][q];
  }
}

// ---------------------------------------------------------------------------
// Gather (fp32 strided source, raw fallback)
// ---------------------------------------------------------------------------
__global__ __launch_bounds__(256)
void k_gather_f(const float* __restrict__ src, const float* __restrict__ wgt,
                const int* __restrict__ widx, float* __restrict__ out,
                long n_stride, long ch_stride)
{
  __shared__ float sw[8][TOPK];
  __shared__ int   si[8][TOPK];
  __shared__ float sbuf[256][9];
  const int p0 = blockIdx.x * 8, chg = blockIdx.y * 256;
  const int tid = threadIdx.x;

  for (int i = tid; i < 8 * TOPK; i += 256) {
    int q = i / TOPK, k = i - q * TOPK;
    sw[q][k] = wgt [(size_t)(p0 + q) * 32 + k];
    si[q][k] = widx[(size_t)(p0 + q) * 32 + k];
  }
  __syncthreads();

  const int ch = chg + tid;
  #pragma unroll 2
  for (int q = 0; q < 8; ++q) {
    float a = 0.f;
    #pragma unroll
    for (int k = 0; k < TOPK; ++k)
      a = fmaf(sw[q][k], src[(size_t)si[q][k] * n_stride + (size_t)ch * ch_stride], a);
    sbuf[tid][q] = a;
  }
  __syncthreads();

  for (int i = tid; i < 256 * 8; i += 256) {
    int cl = i >> 3, q = i & 7;
    out[(size_t)(chg + cl) * HW + p0 + q] = sbuf[cl][q];
  }
}

// ---------------------------------------------------------------------------
extern "C" void kernel_launch(void* const* d_in, const int* in_sizes, int n_in,
                              void* d_out, int out_size, void* d_ws, size_t ws_size,
                              hipStream_t stream)
{
  (void)in_sizes; (void)n_in; (void)out_size;
  const float* q_key     = (const float*)d_in[0];
  const float* q_sel     = (const float*)d_in[1];
  const float* mem_key   = (const float*)d_in[2];
  const float* mem_shr   = (const float*)d_in[3];
  const float* mem_value = (const float*)d_in[4];
  float* out = (float*)d_out;

  char* ws = (char*)d_ws;
  size_t off = 0;
  auto alloc = [&](size_t b) { size_t c = off; off = (off + b + 255) & ~(size_t)255; return c; };
  size_t o_w   = alloc((size_t)HW * 32 * 4);
  size_t o_wi  = alloc((size_t)HW * 32 * 4);
  size_t o_pr  = off;                              // overlay point (fallback)
  size_t o_bh  = alloc((size_t)NMEM * 128 * 2);    // 7.34 MB
  size_t o_uh  = alloc((size_t)HW * 128 * 2);
  size_t o_ul  = alloc((size_t)HW * 128 * 2);
  size_t o_bsq = alloc((size_t)HW * 4);
  size_t o_shr = alloc((size_t)NMEM * 4);
  size_t o_mkT = alloc((size_t)NMEM * 64 * 4);     // 7.34 MB
  size_t o_pm  = alloc((size_t)HW * NCHUNK * 4);   // 25.7 MB
  size_t o_end = off;

  float*          wg   = (float*)(ws + o_w);
  int*            wi   = (int*)  (ws + o_wi);
  unsigned short* Bh   = (unsigned short*)(ws + o_bh);
  unsigned short* Uh   = (unsigned short*)(ws + o_uh);
  unsigned short* Ul   = (unsigned short*)(ws + o_ul);
  float*          bsq  = (float*)(ws + o_bsq);
  float*          shr  = (float*)(ws + o_shr);
  float*          mkT  = (float*)(ws + o_mkT);
  float*          pmx  = (float*)(ws + o_pm);

  const size_t mvh_sz = (size_t)NMEM * 1024 * 2;   // 58.7 MB fp16

  k_prep_b<<<NMEM / 256, 256, 0, stream>>>(mem_key, mem_shr, Bh, mkT, shr);
  k_prep_u<<<HW / 256, 256, 0, stream>>>(q_key, q_sel, Uh, Ul, bsq);
  k_sim<<<SIMB, 256, 0, stream>>>(Uh, Ul, Bh, bsq, shr, pmx);

  if (ws_size >= o_end + mvh_sz) {
    _Float16* mvT = (_Float16*)(ws + o_end);
    k_transpose_h<<<dim3(NMEM / 64, 16), 256, 0, stream>>>(mem_value, mvT);
    k_select<<<HW / 4, 256, 0, stream>>>(pmx, mkT, q_key, q_sel, shr, wg, wi);
    k_gather_h<<<dim3(HW / 8, 4), 256, 0, stream>>>(mvT, wg, wi, out);
  } else if (ws_size >= o_pr + mvh_sz) {
    k_select<<<HW / 4, 256, 0, stream>>>(pmx, mkT, q_key, q_sel, shr, wg, wi);
    _Float16* mvT = (_Float16*)(ws + o_pr);        // Bh..pmx dead after select
    k_transpose_h<<<dim3(NMEM / 64, 16), 256, 0, stream>>>(mem_value, mvT);
    k_gather_h<<<dim3(HW / 8, 4), 256, 0, stream>>>(mvT, wg, wi, out);
  } else {
    k_select<<<HW / 4, 256, 0, stream>>>(pmx, mkT, q_key, q_sel, shr, wg, wi);
    k_gather_f<<<dim3(HW / 8, 4), 256, 0, stream>>>(
        mem_value, wg, wi, out, 1, NMEM);
  }
}